// Round 5
// baseline (124.421 us; speedup 1.0000x reference)
//
#include <hip/hip_runtime.h>

#define HID 128
#define NODE_PAD 50048   // padded node count (multiple of 16; covers 50000)
#define NRANGE 4         // node ranges (LDS histogram per range)
#define RANGE 12512      // NODE_PAD / NRANGE  (48.9 KB of LDS bins)
#define NPART 64         // edge chunks = partial aggregate buffers
#define NGRP 8           // reduced partial groups read by the MLP
#define NRED (NGRP * ((NODE_PAD / 8 + 255) / 256))   // 200 reduce blocks

typedef __attribute__((ext_vector_type(8))) short short8;   // bf16x8 (4 VGPRs)
typedef __attribute__((ext_vector_type(4))) float floatx4;  // C/D frag

// fp32 -> bf16 (RNE) as raw short
__device__ __forceinline__ short f2bf(float f) {
    unsigned u = __builtin_bit_cast(unsigned, f);
    unsigned r = (u + 0x7FFFu + ((u >> 16) & 1u)) >> 16;
    return (short)r;
}
// bf16 (raw short) -> fp32
__device__ __forceinline__ float bf2f(short s) {
    unsigned u = ((unsigned)(unsigned short)s) << 16;
    return __builtin_bit_cast(float, u);
}

// ---------------------------------------------------------------------------
// Kernel 1: scatter-add with ZERO global atomics (round-3 lesson: device
// fp32 atomics bottleneck at ~19 G/s with 32 B write-through each).
// Block (r,b) bins node range r of edge chunk b into fp32 LDS, then streams
// the bins to part[b] as BF16.  XCD swizzle (round-10) co-locates a chunk's
// 4 range-blocks on one XCD so 3 of 4 chunk scans hit L2.
// Round-11: 1024 threads/block.  Unchanged since.
// ---------------------------------------------------------------------------
__global__ __launch_bounds__(1024) void scatter_lds(const int* __restrict__ rows,
                                                    const float* __restrict__ dist,
                                                    unsigned short* __restrict__ part,
                                                    int n_edges) {
    __shared__ float bins[RANGE];
    const int i = blockIdx.x;                      // 0..255
    const int b = (i & 7) * (NPART / 8) + (i >> 5);   // chunk, co-located per XCD
    const int r = (i >> 3) & (NRANGE - 1);            // node range
    const int base = r * RANGE;

    for (int t = threadIdx.x; t < RANGE / 4; t += 1024)
        ((float4*)bins)[t] = make_float4(0.f, 0.f, 0.f, 0.f);
    __syncthreads();

    const int chunk = (n_edges + NPART - 1) / NPART;
    const int cbeg = b * chunk;
    const int cend = min(cbeg + chunk, n_edges);

    for (int e = cbeg + threadIdx.x * 4; e < cend; e += 1024 * 4) {
        if (e + 4 <= cend) {
            int4   rr = *(const int4*)(rows + e);
            float4 dd = *(const float4*)(dist + e);
            if ((unsigned)(rr.x - base) < RANGE) atomicAdd(&bins[rr.x - base], dd.x);
            if ((unsigned)(rr.y - base) < RANGE) atomicAdd(&bins[rr.y - base], dd.y);
            if ((unsigned)(rr.z - base) < RANGE) atomicAdd(&bins[rr.z - base], dd.z);
            if ((unsigned)(rr.w - base) < RANGE) atomicAdd(&bins[rr.w - base], dd.w);
        } else {
            for (int j = e; j < cend; ++j) {
                int rw = rows[j];
                if ((unsigned)(rw - base) < RANGE) atomicAdd(&bins[rw - base], dist[j]);
            }
        }
    }
    __syncthreads();

    unsigned short* dst = part + (size_t)b * NODE_PAD + base;
    for (int t = threadIdx.x; t < RANGE / 8; t += 1024) {
        float4 lo = ((const float4*)bins)[t * 2];
        float4 hi = ((const float4*)bins)[t * 2 + 1];
        short8 v;
        v[0] = f2bf(lo.x); v[1] = f2bf(lo.y); v[2] = f2bf(lo.z); v[3] = f2bf(lo.w);
        v[4] = f2bf(hi.x); v[5] = f2bf(hi.y); v[6] = f2bf(hi.z); v[7] = f2bf(hi.w);
        *(short8*)(dst + t * 8) = v;
    }
}

// ---------------------------------------------------------------------------
// Kernel 2: reduce the 64 bf16 partials down to NGRP=8 fp32 groups (8 each),
// PLUS 2 tail blocks that pre-transpose W1/W2 into bf16 fragment layout
// WT[col][k].  Stream order guarantees completion before k3.
// ---------------------------------------------------------------------------
__global__ __launch_bounds__(256) void reduce_partials(
    const unsigned short* __restrict__ part,
    float* __restrict__ agg4,
    const float* __restrict__ W1,
    const float* __restrict__ W2,
    unsigned short* __restrict__ WT1,
    unsigned short* __restrict__ WT2) {
    if (blockIdx.x >= NRED) {
        // ---- weight transpose+convert: WT[col][k] = bf16(W[k][col])
        const float* W = (blockIdx.x == NRED) ? W1 : W2;
        unsigned short* WT = (blockIdx.x == NRED) ? WT1 : WT2;
        const int col = threadIdx.x & 127;          // lanes 0..63 -> coalesced
        const int kh  = (threadIdx.x >> 7) * 64;    // k half owned by thread
#pragma unroll
        for (int k8 = 0; k8 < 8; ++k8) {
            short8 v;
#pragma unroll
            for (int j = 0; j < 8; ++j)
                v[j] = f2bf(W[(size_t)(kh + k8 * 8 + j) * HID + col]);
            *(short8*)(WT + (size_t)col * HID + kh + k8 * 8) = v;
        }
        return;
    }
    const int g   = blockIdx.x & (NGRP - 1);
    const int idx = (blockIdx.x >> 3) * 256 + threadIdx.x;   // 8-node group
    const int n8  = NODE_PAD / 8;
    if (idx < n8) {
        float s[8] = {0.f, 0.f, 0.f, 0.f, 0.f, 0.f, 0.f, 0.f};
#pragma unroll
        for (int c = 0; c < NPART / NGRP; ++c) {
            const unsigned short* p =
                part + (size_t)(g * (NPART / NGRP) + c) * NODE_PAD + idx * 8;
            short8 v = *(const short8*)p;
#pragma unroll
            for (int j = 0; j < 8; ++j) s[j] += bf2f(v[j]);
        }
        float* o = agg4 + (size_t)g * NODE_PAD + idx * 8;
        *(float4*)o       = make_float4(s[0], s[1], s[2], s[3]);
        *(float4*)(o + 4) = make_float4(s[4], s[5], s[6], s[7]);
    }
}

// ---------------------------------------------------------------------------
// Kernel 3 (round-15): round-14 structure + residual-from-registers.
// The h row loaded for the A-fragments is KEPT in fp32 regs (hkeep, 32
// VGPR — replacing the 32-VGPR hv[] of round-14) and the 25.6 MB residual
// re-read of h is deleted.  The epilogue read side switches from (erow,ecg)
// to the OWNING-lane distribution: for tile nt, quads with quad>>1 == nt&1
// read 8 cols (nt*16+(quad&1)*8..+7) from their own scratch row m16; the
// residual value is hkeep[nt>>1][jj] — all indices compile-time (no
// dynamic-index spill), zero shuffles, identical 16x64B store coalescing.
// b1/wagg/b2 scalars loaded at point of use (L2-hot) to hold VGPR <= 128
// (launch_bounds(512,4) -> 2 blocks/CU = 16 waves/CU).
//   t = silu(h@W1 + agg*0.01*w_agg + b1); out = h + t@W2 + b2
// ---------------------------------------------------------------------------
__global__ __launch_bounds__(512, 4) void node_mlp_mfma(
    const float* __restrict__ h,
    const float* __restrict__ agg4,          // [NGRP][NODE_PAD]
    const unsigned short* __restrict__ WT1,  // [128][128] bf16, [col][k]
    const unsigned short* __restrict__ WT2,  // [128][128] bf16, [col][k]
    const float* __restrict__ W1,            // fp32, only row 128 (agg w) used
    const float* __restrict__ b1,
    const float* __restrict__ b2,
    float* __restrict__ out,
    int n_nodes)
{
    __shared__ short WL[128 * 136];        // 34816 B, one layer at a time
    __shared__ short t_lds[8][16 * 136];   // 34816 B, per-wave t / scratch

    const int tid  = threadIdx.x;
    const int wv   = tid >> 6;
    const int lane = tid & 63;
    const int m16  = lane & 15;
    const int quad = lane >> 4;
    const int node0 = blockIdx.x * 128 + wv * 16;

    // ---- T14 async W2 prefetch: issue global loads NOW; the vmcnt wait
    // lands at the ds_write after barrier 2, hidden under layer-1 compute.
    short8 w2r[4];
#pragma unroll
    for (int i = 0; i < 4; ++i)
        w2r[i] = ((const short8*)WT2)[tid + i * 512];

    // ---- A fragments for layer 1; KEEP the fp32 row (hkeep) for the
    // residual — no second h read.
    short8 a1[4];
    float hkeep[4][8];   // [kc][j] = h[row][quad*8 + kc*32 + j], fp32
    const bool rvalid = (node0 + m16) < n_nodes;
    {
        int row = node0 + m16;
        if (row >= n_nodes) row = n_nodes - 1;
        const float* hr = h + (size_t)row * HID + quad * 8;
#pragma unroll
        for (int kc = 0; kc < 4; ++kc) {
            float4 x0 = *(const float4*)(hr + kc * 32);
            float4 x1 = *(const float4*)(hr + kc * 32 + 4);
            hkeep[kc][0] = x0.x; hkeep[kc][1] = x0.y;
            hkeep[kc][2] = x0.z; hkeep[kc][3] = x0.w;
            hkeep[kc][4] = x1.x; hkeep[kc][5] = x1.y;
            hkeep[kc][6] = x1.z; hkeep[kc][7] = x1.w;
            short8 v;
            v[0] = f2bf(x0.x); v[1] = f2bf(x0.y); v[2] = f2bf(x0.z); v[3] = f2bf(x0.w);
            v[4] = f2bf(x1.x); v[5] = f2bf(x1.y); v[6] = f2bf(x1.z); v[7] = f2bf(x1.w);
            a1[kc] = v;
        }
    }

    // ---- stage W1 -> LDS: linear bf16 copy into 136-pitch layout.
#pragma unroll
    for (int t = tid; t < 128 * 16; t += 512) {
        short8 v = ((const short8*)WT1)[t];
        *(short8*)(WL + (t >> 4) * 136 + (t & 15) * 8) = v;
    }

    // agg for this lane's 4 C-rows: sum the NGRP reduced groups, scale by 1/100
    float4 a4;
    {
        float4 s = make_float4(0.f, 0.f, 0.f, 0.f);
#pragma unroll
        for (int g = 0; g < NGRP; ++g) {
            float4 p = *(const float4*)(agg4 + (size_t)g * NODE_PAD + node0 + quad * 4);
            s.x += p.x; s.y += p.y; s.z += p.z; s.w += p.w;
        }
        a4.x = s.x * 0.01f; a4.y = s.y * 0.01f; a4.z = s.z * 0.01f; a4.w = s.w * 0.01f;
    }
    __syncthreads();

    // ---- layer 1: 8 col-tiles of 16, K=128 in 4 MFMA steps each
#pragma unroll
    for (int nt = 0; nt < 8; ++nt) {
        floatx4 acc = {0.f, 0.f, 0.f, 0.f};
        const short* wb = WL + (nt * 16 + m16) * 136 + quad * 8;
#pragma unroll
        for (int kc = 0; kc < 4; ++kc) {
            short8 bfr = *(const short8*)(wb + kc * 32);
            acc = __builtin_amdgcn_mfma_f32_16x16x32_bf16(a1[kc], bfr, acc, 0, 0, 0);
        }
        int col = nt * 16 + m16;
        float bias = b1[col];                       // L2-hot
        float wagg = W1[(size_t)HID * HID + col];   // W1 row 128 (agg weight)
        float av[4] = {a4.x, a4.y, a4.z, a4.w};
#pragma unroll
        for (int r = 0; r < 4; ++r) {
            float v = acc[r] + bias + av[r] * wagg;
            float sg = __builtin_amdgcn_rcpf(1.0f + __expf(-v));
            v *= sg;                       // silu
            t_lds[wv][(quad * 4 + r) * 136 + col] = f2bf(v);
        }
    }

    __syncthreads();   // all waves done reading W1 before overwrite

    // ---- A fragments for layer 2 from own LDS slice (A-layout, 16B aligned)
    short8 a2[4];
#pragma unroll
    for (int kc = 0; kc < 4; ++kc)
        a2[kc] = *(const short8*)(&t_lds[wv][m16 * 136 + kc * 32 + quad * 8]);

    // ---- W2 regs -> LDS (no global load on the critical path)
#pragma unroll
    for (int i = 0; i < 4; ++i) {
        int t = tid + i * 512;
        *(short8*)(WL + (t >> 4) * 136 + (t & 15) * 8) = w2r[i];
    }
    __syncthreads();

    // ---- layer 2 + residual epilogue, owning-lane read side.
    // Scratch (wave-private, reuses consumed t slice; per-wave DS in-order,
    // no barrier).  For tile nt: all lanes write C+bias; the 32 lanes with
    // quad>>1 == nt&1 read back their own row m16, add hkeep, store.
    float* scratch = (float*)&t_lds[wv][0];   // 16 rows x 17 fp32 (1088 B)
    const int ql = quad & 1;
    const int qh = quad >> 1;
#pragma unroll
    for (int nt = 0; nt < 8; ++nt) {
        floatx4 acc = {0.f, 0.f, 0.f, 0.f};
        const short* wb = WL + (nt * 16 + m16) * 136 + quad * 8;
#pragma unroll
        for (int kc = 0; kc < 4; ++kc) {
            short8 bfr = *(const short8*)(wb + kc * 32);
            acc = __builtin_amdgcn_mfma_f32_16x16x32_bf16(a2[kc], bfr, acc, 0, 0, 0);
        }
        // C-layout (col=m16, row=quad*4+r) -> scratch, bias fused
        float b2c = b2[nt * 16 + m16];
#pragma unroll
        for (int r = 0; r < 4; ++r)
            scratch[(quad * 4 + r) * 17 + m16] = acc[r] + b2c;
        // owning-lane readback: cols nt*16+ql*8..+7 of row m16
        if (qh == (nt & 1) && rvalid) {
            const int kc = nt >> 1;               // compile-time per nt
            float4 s0 = *(const float4*)(scratch + m16 * 17 + ql * 8);
            float4 s1 = *(const float4*)(scratch + m16 * 17 + ql * 8 + 4);
            size_t off = (size_t)(node0 + m16) * HID + nt * 16 + ql * 8;
            float4 o0 = make_float4(hkeep[kc][0] + s0.x, hkeep[kc][1] + s0.y,
                                    hkeep[kc][2] + s0.z, hkeep[kc][3] + s0.w);
            float4 o1 = make_float4(hkeep[kc][4] + s1.x, hkeep[kc][5] + s1.y,
                                    hkeep[kc][6] + s1.z, hkeep[kc][7] + s1.w);
            *(float4*)(out + off)     = o0;
            *(float4*)(out + off + 4) = o1;
        }
    }
}

// ---------------------------------------------------------------------------
// Launch.  Inputs (setup_inputs order):
//  0 h[50000*128] f32 | 1 edges[2*800000] i32 | 2 distances[800000] f32
//  3..8 edge-MLP weights (DEAD CODE, unused)
//  9 W_n1[129*128] | 10 b_n1[128] | 11 W_n2[128*128] | 12 b_n2[128]
// d_ws: part bf16[NPART][NODE_PAD] (6.4 MB) | agg4 f32[NGRP][NODE_PAD]
//       (1.6 MB) | WT1 bf16[128*128] (32 KB) | WT2 bf16[128*128] (32 KB).
// No zeroing needed: every element is overwritten.
// ---------------------------------------------------------------------------
extern "C" void kernel_launch(void* const* d_in, const int* in_sizes, int n_in,
                              void* d_out, int out_size, void* d_ws, size_t ws_size,
                              hipStream_t stream) {
    const float* h     = (const float*)d_in[0];
    const int*   edges = (const int*)d_in[1];
    const float* dist  = (const float*)d_in[2];
    const float* W1    = (const float*)d_in[9];
    const float* b1    = (const float*)d_in[10];
    const float* W2    = (const float*)d_in[11];
    const float* b2    = (const float*)d_in[12];
    float* out = (float*)d_out;

    const int n_nodes = in_sizes[0] / HID;
    const int n_edges = in_sizes[2];
    const int* rows = edges;   // edges[0, :]

    unsigned short* part = (unsigned short*)d_ws;
    float* agg4 = (float*)(part + (size_t)NPART * NODE_PAD);
    unsigned short* WT1 = (unsigned short*)(agg4 + (size_t)NGRP * NODE_PAD);
    unsigned short* WT2 = WT1 + HID * HID;

    scatter_lds<<<NRANGE * NPART, 1024, 0, stream>>>(rows, dist, part, n_edges);

    reduce_partials<<<NRED + 2, 256, 0, stream>>>(part, agg4, W1, W2, WT1, WT2);

    const int blocks = (n_nodes + 127) / 128;
    node_mlp_mfma<<<blocks, 512, 0, stream>>>(h, agg4, WT1, WT2, W1, b1, b2, out, n_nodes);
}

// Round 6
// 123.364 us; speedup vs baseline: 1.0086x; 1.0086x over previous
//
#include <hip/hip_runtime.h>

#define HID 128
#define NODE_PAD 50048   // padded node count (multiple of 16; covers 50000)
#define NRANGE 4         // node ranges (LDS histogram per range)
#define RANGE 12512      // NODE_PAD / NRANGE  (48.9 KB of LDS bins)
#define NPART 64         // edge chunks = partial aggregate buffers
#define NGB 32           // node-groups (of 8 nodes) per reduce block
#define NSL 8            // chunk slices per reduce block (NSL*8 = NPART)
#define N8  (NODE_PAD / 8)                    // 6256 node-groups
#define NRED ((N8 + NGB - 1) / NGB)           // 196 reduce blocks

typedef __attribute__((ext_vector_type(8))) short short8;   // bf16x8 (4 VGPRs)
typedef __attribute__((ext_vector_type(4))) float floatx4;  // C/D frag

// fp32 -> bf16 (RNE) as raw short
__device__ __forceinline__ short f2bf(float f) {
    unsigned u = __builtin_bit_cast(unsigned, f);
    unsigned r = (u + 0x7FFFu + ((u >> 16) & 1u)) >> 16;
    return (short)r;
}
// bf16 (raw short) -> fp32
__device__ __forceinline__ float bf2f(short s) {
    unsigned u = ((unsigned)(unsigned short)s) << 16;
    return __builtin_bit_cast(float, u);
}

// ---------------------------------------------------------------------------
// Kernel 1: scatter-add with ZERO global atomics.  Block (r,b) bins node
// range r of edge chunk b into fp32 LDS, then streams the bins to part[b]
// as BF16.  XCD swizzle co-locates a chunk's 4 range-blocks on one XCD.
// Round-16: +2 tail blocks (ids 256,257) do the W1/W2 transpose+convert
// here (one kernel earlier than round-15) so WT is L2-warm before k3's
// prefetch regardless of k2 timing.  Main path unchanged.
// ---------------------------------------------------------------------------
__global__ __launch_bounds__(1024) void scatter_lds(const int* __restrict__ rows,
                                                    const float* __restrict__ dist,
                                                    unsigned short* __restrict__ part,
                                                    const float* __restrict__ W1,
                                                    const float* __restrict__ W2,
                                                    unsigned short* __restrict__ WT1,
                                                    unsigned short* __restrict__ WT2,
                                                    int n_edges) {
    __shared__ float bins[RANGE];
    const int i = blockIdx.x;                      // 0..257
    if (i >= NRANGE * NPART) {
        // ---- weight transpose+convert: WT[col][k] = bf16(W[k][col])
        const float* W = (i == NRANGE * NPART) ? W1 : W2;
        unsigned short* WT = (i == NRANGE * NPART) ? WT1 : WT2;
        const int col = threadIdx.x & 127;          // coalesced over cols
        const int ke  = (threadIdx.x >> 7) * 16;    // 16-k span per thread
#pragma unroll
        for (int k8 = 0; k8 < 2; ++k8) {
            short8 v;
#pragma unroll
            for (int j = 0; j < 8; ++j)
                v[j] = f2bf(W[(size_t)(ke + k8 * 8 + j) * HID + col]);
            *(short8*)(WT + (size_t)col * HID + ke + k8 * 8) = v;
        }
        return;
    }
    const int b = (i & 7) * (NPART / 8) + (i >> 5);   // chunk, co-located per XCD
    const int r = (i >> 3) & (NRANGE - 1);            // node range
    const int base = r * RANGE;

    for (int t = threadIdx.x; t < RANGE / 4; t += 1024)
        ((float4*)bins)[t] = make_float4(0.f, 0.f, 0.f, 0.f);
    __syncthreads();

    const int chunk = (n_edges + NPART - 1) / NPART;
    const int cbeg = b * chunk;
    const int cend = min(cbeg + chunk, n_edges);

    for (int e = cbeg + threadIdx.x * 4; e < cend; e += 1024 * 4) {
        if (e + 4 <= cend) {
            int4   rr = *(const int4*)(rows + e);
            float4 dd = *(const float4*)(dist + e);
            if ((unsigned)(rr.x - base) < RANGE) atomicAdd(&bins[rr.x - base], dd.x);
            if ((unsigned)(rr.y - base) < RANGE) atomicAdd(&bins[rr.y - base], dd.y);
            if ((unsigned)(rr.z - base) < RANGE) atomicAdd(&bins[rr.z - base], dd.z);
            if ((unsigned)(rr.w - base) < RANGE) atomicAdd(&bins[rr.w - base], dd.w);
        } else {
            for (int j = e; j < cend; ++j) {
                int rw = rows[j];
                if ((unsigned)(rw - base) < RANGE) atomicAdd(&bins[rw - base], dist[j]);
            }
        }
    }
    __syncthreads();

    unsigned short* dst = part + (size_t)b * NODE_PAD + base;
    for (int t = threadIdx.x; t < RANGE / 8; t += 1024) {
        float4 lo = ((const float4*)bins)[t * 2];
        float4 hi = ((const float4*)bins)[t * 2 + 1];
        short8 v;
        v[0] = f2bf(lo.x); v[1] = f2bf(lo.y); v[2] = f2bf(lo.z); v[3] = f2bf(lo.w);
        v[4] = f2bf(hi.x); v[5] = f2bf(hi.y); v[6] = f2bf(hi.z); v[7] = f2bf(hi.w);
        *(short8*)(dst + t * 8) = v;
    }
}

// ---------------------------------------------------------------------------
// Kernel 2 (round-16): FULL 64-partial reduce to a single fp32 agg[NODE_PAD].
// 256 threads = NGB=32 node-groups x NSL=8 chunk-slices; each thread sums 8
// partials (short8 loads, fp32 acc), LDS tree-combine across slices (bank
// stride 256 floats -> 2-way access, free), coalesced 4B stores.
// Removes 7 of k3's 8 strided agg loads from its pre-barrier latency chain.
// Reassociation (8x8 tree vs 8-chain-of-8-groups) is far below the bf16
// quantization already in part[].
// ---------------------------------------------------------------------------
__global__ __launch_bounds__(256) void reduce_partials(
    const unsigned short* __restrict__ part,
    float* __restrict__ agg) {
    __shared__ float acc_lds[NSL * NGB * 8];   // [slice][ng][8] = 8 KB

    const int sl = threadIdx.x >> 5;           // 0..7 chunk slice
    const int ngl = threadIdx.x & 31;          // 0..31 local node-group
    const int ng = blockIdx.x * NGB + ngl;     // global node-group (8 nodes)

    float s[8] = {0.f, 0.f, 0.f, 0.f, 0.f, 0.f, 0.f, 0.f};
    if (ng < N8) {
#pragma unroll
        for (int c = 0; c < NPART / NSL; ++c) {
            const unsigned short* p =
                part + (size_t)(sl * (NPART / NSL) + c) * NODE_PAD + ng * 8;
            short8 v = *(const short8*)p;
#pragma unroll
            for (int j = 0; j < 8; ++j) s[j] += bf2f(v[j]);
        }
    }
#pragma unroll
    for (int j = 0; j < 8; ++j) acc_lds[sl * (NGB * 8) + ngl * 8 + j] = s[j];
    __syncthreads();

    // thread t -> one node value: node = blk*256 + t, sum over 8 slices
    const int t = threadIdx.x;
    float v = 0.f;
#pragma unroll
    for (int slc = 0; slc < NSL; ++slc) v += acc_lds[slc * (NGB * 8) + t];
    const int node = blockIdx.x * (NGB * 8) + t;
    if (node < NODE_PAD) agg[node] = v;
}

// ---------------------------------------------------------------------------
// Kernel 3 (round-16): round-15 structure, single-agg load.
//  - T14 async W2 prefetch at kernel start (ds_write after barrier 2).
//  - h row kept in fp32 regs (hkeep) for the residual; no second h read.
//  - agg phase is now ONE float4 load (was 8 strided group loads) --
//    shortens the pre-barrier VMEM chain, frees ~24 VGPRs.
//  - owning-lane epilogue readback (round-15), all compile-time indices.
//   t = silu(h@W1 + agg*0.01*w_agg + b1); out = h + t@W2 + b2
// ---------------------------------------------------------------------------
__global__ __launch_bounds__(512, 4) void node_mlp_mfma(
    const float* __restrict__ h,
    const float* __restrict__ agg,           // fp32[NODE_PAD], fully reduced
    const unsigned short* __restrict__ WT1,  // [128][128] bf16, [col][k]
    const unsigned short* __restrict__ WT2,  // [128][128] bf16, [col][k]
    const float* __restrict__ W1,            // fp32, only row 128 (agg w) used
    const float* __restrict__ b1,
    const float* __restrict__ b2,
    float* __restrict__ out,
    int n_nodes)
{
    __shared__ short WL[128 * 136];        // 34816 B, one layer at a time
    __shared__ short t_lds[8][16 * 136];   // 34816 B, per-wave t / scratch

    const int tid  = threadIdx.x;
    const int wv   = tid >> 6;
    const int lane = tid & 63;
    const int m16  = lane & 15;
    const int quad = lane >> 4;
    const int node0 = blockIdx.x * 128 + wv * 16;

    // ---- T14 async W2 prefetch
    short8 w2r[4];
#pragma unroll
    for (int i = 0; i < 4; ++i)
        w2r[i] = ((const short8*)WT2)[tid + i * 512];

    // ---- A fragments for layer 1; KEEP the fp32 row (hkeep) for residual
    short8 a1[4];
    float hkeep[4][8];   // [kc][j] = h[row][quad*8 + kc*32 + j], fp32
    const bool rvalid = (node0 + m16) < n_nodes;
    {
        int row = node0 + m16;
        if (row >= n_nodes) row = n_nodes - 1;
        const float* hr = h + (size_t)row * HID + quad * 8;
#pragma unroll
        for (int kc = 0; kc < 4; ++kc) {
            float4 x0 = *(const float4*)(hr + kc * 32);
            float4 x1 = *(const float4*)(hr + kc * 32 + 4);
            hkeep[kc][0] = x0.x; hkeep[kc][1] = x0.y;
            hkeep[kc][2] = x0.z; hkeep[kc][3] = x0.w;
            hkeep[kc][4] = x1.x; hkeep[kc][5] = x1.y;
            hkeep[kc][6] = x1.z; hkeep[kc][7] = x1.w;
            short8 v;
            v[0] = f2bf(x0.x); v[1] = f2bf(x0.y); v[2] = f2bf(x0.z); v[3] = f2bf(x0.w);
            v[4] = f2bf(x1.x); v[5] = f2bf(x1.y); v[6] = f2bf(x1.z); v[7] = f2bf(x1.w);
            a1[kc] = v;
        }
    }

    // ---- stage W1 -> LDS: linear bf16 copy into 136-pitch layout.
#pragma unroll
    for (int t = tid; t < 128 * 16; t += 512) {
        short8 v = ((const short8*)WT1)[t];
        *(short8*)(WL + (t >> 4) * 136 + (t & 15) * 8) = v;
    }

    // agg for this lane's 4 C-rows: ONE float4, pre-scaled by 1/100
    float4 a4;
    {
        float4 p = *(const float4*)(agg + node0 + quad * 4);
        a4.x = p.x * 0.01f; a4.y = p.y * 0.01f;
        a4.z = p.z * 0.01f; a4.w = p.w * 0.01f;
    }
    __syncthreads();

    // ---- layer 1: 8 col-tiles of 16, K=128 in 4 MFMA steps each
#pragma unroll
    for (int nt = 0; nt < 8; ++nt) {
        floatx4 acc = {0.f, 0.f, 0.f, 0.f};
        const short* wb = WL + (nt * 16 + m16) * 136 + quad * 8;
#pragma unroll
        for (int kc = 0; kc < 4; ++kc) {
            short8 bfr = *(const short8*)(wb + kc * 32);
            acc = __builtin_amdgcn_mfma_f32_16x16x32_bf16(a1[kc], bfr, acc, 0, 0, 0);
        }
        int col = nt * 16 + m16;
        float bias = b1[col];                       // L2-hot
        float wagg = W1[(size_t)HID * HID + col];   // W1 row 128 (agg weight)
        float av[4] = {a4.x, a4.y, a4.z, a4.w};
#pragma unroll
        for (int r = 0; r < 4; ++r) {
            float v = acc[r] + bias + av[r] * wagg;
            float sg = __builtin_amdgcn_rcpf(1.0f + __expf(-v));
            v *= sg;                       // silu
            t_lds[wv][(quad * 4 + r) * 136 + col] = f2bf(v);
        }
    }

    __syncthreads();   // all waves done reading W1 before overwrite

    // ---- A fragments for layer 2 from own LDS slice (A-layout, 16B aligned)
    short8 a2[4];
#pragma unroll
    for (int kc = 0; kc < 4; ++kc)
        a2[kc] = *(const short8*)(&t_lds[wv][m16 * 136 + kc * 32 + quad * 8]);

    // ---- W2 regs -> LDS (no global load on the critical path)
#pragma unroll
    for (int i = 0; i < 4; ++i) {
        int t = tid + i * 512;
        *(short8*)(WL + (t >> 4) * 136 + (t & 15) * 8) = w2r[i];
    }
    __syncthreads();

    // ---- layer 2 + residual epilogue, owning-lane read side (round-15).
    float* scratch = (float*)&t_lds[wv][0];   // 16 rows x 17 fp32 (1088 B)
    const int ql = quad & 1;
    const int qh = quad >> 1;
#pragma unroll
    for (int nt = 0; nt < 8; ++nt) {
        floatx4 acc = {0.f, 0.f, 0.f, 0.f};
        const short* wb = WL + (nt * 16 + m16) * 136 + quad * 8;
#pragma unroll
        for (int kc = 0; kc < 4; ++kc) {
            short8 bfr = *(const short8*)(wb + kc * 32);
            acc = __builtin_amdgcn_mfma_f32_16x16x32_bf16(a2[kc], bfr, acc, 0, 0, 0);
        }
        // C-layout (col=m16, row=quad*4+r) -> scratch, bias fused
        float b2c = b2[nt * 16 + m16];
#pragma unroll
        for (int r = 0; r < 4; ++r)
            scratch[(quad * 4 + r) * 17 + m16] = acc[r] + b2c;
        // owning-lane readback: cols nt*16+ql*8..+7 of row m16
        if (qh == (nt & 1) && rvalid) {
            const int kc = nt >> 1;               // compile-time per nt
            float4 s0 = *(const float4*)(scratch + m16 * 17 + ql * 8);
            float4 s1 = *(const float4*)(scratch + m16 * 17 + ql * 8 + 4);
            size_t off = (size_t)(node0 + m16) * HID + nt * 16 + ql * 8;
            float4 o0 = make_float4(hkeep[kc][0] + s0.x, hkeep[kc][1] + s0.y,
                                    hkeep[kc][2] + s0.z, hkeep[kc][3] + s0.w);
            float4 o1 = make_float4(hkeep[kc][4] + s1.x, hkeep[kc][5] + s1.y,
                                    hkeep[kc][6] + s1.z, hkeep[kc][7] + s1.w);
            *(float4*)(out + off)     = o0;
            *(float4*)(out + off + 4) = o1;
        }
    }
}

// ---------------------------------------------------------------------------
// Launch.  Inputs (setup_inputs order):
//  0 h[50000*128] f32 | 1 edges[2*800000] i32 | 2 distances[800000] f32
//  3..8 edge-MLP weights (DEAD CODE, unused)
//  9 W_n1[129*128] | 10 b_n1[128] | 11 W_n2[128*128] | 12 b_n2[128]
// d_ws: part bf16[NPART][NODE_PAD] (6.4 MB) | agg fp32[NODE_PAD] (200 KB)
//       | WT1 bf16[128*128] (32 KB) | WT2 bf16[128*128] (32 KB).
// No zeroing needed: every element is overwritten.
// ---------------------------------------------------------------------------
extern "C" void kernel_launch(void* const* d_in, const int* in_sizes, int n_in,
                              void* d_out, int out_size, void* d_ws, size_t ws_size,
                              hipStream_t stream) {
    const float* h     = (const float*)d_in[0];
    const int*   edges = (const int*)d_in[1];
    const float* dist  = (const float*)d_in[2];
    const float* W1    = (const float*)d_in[9];
    const float* b1    = (const float*)d_in[10];
    const float* W2    = (const float*)d_in[11];
    const float* b2    = (const float*)d_in[12];
    float* out = (float*)d_out;

    const int n_nodes = in_sizes[0] / HID;
    const int n_edges = in_sizes[2];
    const int* rows = edges;   // edges[0, :]

    unsigned short* part = (unsigned short*)d_ws;
    float* agg = (float*)(part + (size_t)NPART * NODE_PAD);
    unsigned short* WT1 = (unsigned short*)(agg + NODE_PAD);
    unsigned short* WT2 = WT1 + HID * HID;

    scatter_lds<<<NRANGE * NPART + 2, 1024, 0, stream>>>(
        rows, dist, part, W1, W2, WT1, WT2, n_edges);

    reduce_partials<<<NRED, 256, 0, stream>>>(part, agg);

    const int blocks = (n_nodes + 127) / 128;
    node_mlp_mfma<<<blocks, 512, 0, stream>>>(h, agg, WT1, WT2, W1, b1, b2, out, n_nodes);
}